// Round 6
// baseline (109.584 us; speedup 1.0000x reference)
//
#include <hip/hip_runtime.h>
#include <math.h>

#define NODE_DIM 128
#define HIDDEN   64
#define NN       2048
#define LSTR     68   // floats per LDS row: 64 data + 4 pad (272 B, 16B-aligned)

typedef float v2f __attribute__((ext_vector_type(2)));
typedef float v4f __attribute__((ext_vector_type(4)));

// ---------------------------------------------------------------------------
// Prep (R1/R5-verbatim math, fp32) + rank-1 sums:
//   h = nf[r] @ W_enc + b_enc
//   A[r]  = h @ W1[:64]          (fp32)
//   BB[r] = h @ W1[64:] + b1     (b1 folded, fp32)
//   pa[r] = sum_h W2[h]*A[r,h]   pb[r] = sum_h W2[h]*BB[r,h]
// Reductions via LDS + single-lane sum (deliberately dumb & correct —
// no shuffles, no dot intrinsics).
// ---------------------------------------------------------------------------
__global__ __launch_bounds__(256) void prep_kernel(
    const float* __restrict__ nf, const float* __restrict__ W_enc,
    const float* __restrict__ b_enc, const float* __restrict__ W1,
    const float* __restrict__ b1, const float* __restrict__ W2,
    float* __restrict__ A, float* __restrict__ BB,
    float* __restrict__ pa, float* __restrict__ pb)
{
    __shared__ float nf_s[4][NODE_DIM];
    __shared__ float h_s[4][HIDDEN];
    __shared__ float ra_s[4][HIDDEN];
    __shared__ float rb_s[4][HIDDEN];
    const int tid = threadIdx.x;
    const int rg  = tid >> 6;
    const int t   = tid & 63;
    const int r   = blockIdx.x * 4 + rg;

    ((float2*)nf_s[rg])[t] = ((const float2*)(nf + (size_t)r * NODE_DIM))[t];
    __syncthreads();

    float acc = b_enc[t];
    #pragma unroll 8
    for (int k = 0; k < NODE_DIM; ++k)
        acc = fmaf(nf_s[rg][k], W_enc[k * HIDDEN + t], acc);
    h_s[rg][t] = acc;
    __syncthreads();

    float aacc = 0.0f;
    float bacc = b1[t];
    #pragma unroll 8
    for (int k = 0; k < HIDDEN; ++k) {
        const float hv = h_s[rg][k];
        aacc = fmaf(hv, W1[k * HIDDEN + t], aacc);
        bacc = fmaf(hv, W1[(HIDDEN + k) * HIDDEN + t], bacc);
    }
    A[(size_t)r * HIDDEN + t]  = aacc;
    BB[(size_t)r * HIDDEN + t] = bacc;

    const float wv = W2[t];
    ra_s[rg][t] = wv * aacc;
    rb_s[rg][t] = wv * bacc;
    __syncthreads();

    if (t == 0) {
        float sa = 0.0f, sb = 0.0f;
        #pragma unroll 8
        for (int k = 0; k < HIDDEN; ++k) { sa += ra_s[rg][k]; sb += rb_s[rg][k]; }
        pa[r] = sa;
        pb[r] = sb;
    }
}

// ---------------------------------------------------------------------------
// Pairwise:
//   S[i][j]  = sum_h W2[h] * |A[i,h] + BB[j,h]|
//   logit    = b2 + 0.5*(pa[i] + pb[j] + S[i][j])     (relu = (x+|x|)/2)
//   T[i][j]  = sigmoid(logit), diagonal zeroed.
// Block: 128 threads (2 waves), tile 128i x 64j, grid 32x16 = 512 blocks
// (2 blocks/CU -> staging of one block overlaps compute of the other).
// Micro-tile 8x8: i = i0+ty+16*ii (ty 0..15), j = j0+tx+8*jj (tx 0..7).
// Inner loop per 4h per output: 2x v_pk_add_f32 + 4x v_fma_f32 with abs()
// source modifier (w in SGPR) = 1.5 instr/h. No pk_max needed (doesn't
// exist for f32 on CDNA — R5's mistake). LDS reads: 8 distinct rows per
// instr, stride 68 -> bank starts {0,4,...,28}, broadcast within row ->
// conflict-free.
// ---------------------------------------------------------------------------
__global__ __launch_bounds__(128) void pair_kernel(
    const float* __restrict__ A, const float* __restrict__ BB,
    const float* __restrict__ pa, const float* __restrict__ pb,
    const float* __restrict__ W2, const float* __restrict__ b2,
    float* __restrict__ out)
{
    __shared__ __align__(16) float aL[128 * LSTR];   // 34.8 KB
    __shared__ __align__(16) float bL[64 * LSTR];    // 17.4 KB

    const int tid = threadIdx.x;
    const int i0  = blockIdx.y * 128;
    const int j0  = blockIdx.x * 64;

    // ---- stage: A tile 128x64 fp32 (2048 float4), B tile 64x64 (1024) ----
    const v4f* gA = (const v4f*)(A  + (size_t)i0 * HIDDEN);
    const v4f* gB = (const v4f*)(BB + (size_t)j0 * HIDDEN);
    #pragma unroll
    for (int k = 0; k < 16; ++k) {
        const int idx = tid + k * 128;   // 0..2047
        const int row = idx >> 4;        // 16 float4 per row
        const int c   = idx & 15;
        *(v4f*)&aL[row * LSTR + c * 4] = gA[idx];
    }
    #pragma unroll
    for (int k = 0; k < 8; ++k) {
        const int idx = tid + k * 128;   // 0..1023
        const int row = idx >> 4;
        const int c   = idx & 15;
        *(v4f*)&bL[row * LSTR + c * 4] = gB[idx];
    }
    __syncthreads();

    const int ty = tid >> 3;   // 0..15 : i = i0 + ty + 16*ii
    const int tx = tid & 7;    // 0..7  : j = j0 + tx + 8*jj

    float acc[8][8] = {{0.0f}};

    #pragma unroll
    for (int c = 0; c < 16; ++c) {       // 4 h per chunk
        const float w0 = W2[c * 4 + 0];  // uniform -> s_load, SGPR operands
        const float w1 = W2[c * 4 + 1];
        const float w2 = W2[c * 4 + 2];
        const float w3 = W2[c * 4 + 3];
        v4f av[8], bv[8];
        #pragma unroll
        for (int ii = 0; ii < 8; ++ii)
            av[ii] = *(const v4f*)&aL[(ty + 16 * ii) * LSTR + c * 4];
        #pragma unroll
        for (int jj = 0; jj < 8; ++jj)
            bv[jj] = *(const v4f*)&bL[(tx + 8 * jj) * LSTR + c * 4];
        #pragma unroll
        for (int ii = 0; ii < 8; ++ii) {
            #pragma unroll
            for (int jj = 0; jj < 8; ++jj) {
                const v4f t = av[ii] + bv[jj];   // 2x v_pk_add_f32
                float s = acc[ii][jj];
                s = fmaf(__builtin_fabsf(t[0]), w0, s);  // v_fma_f32 abs(src0)
                s = fmaf(__builtin_fabsf(t[1]), w1, s);
                s = fmaf(__builtin_fabsf(t[2]), w2, s);
                s = fmaf(__builtin_fabsf(t[3]), w3, s);
                acc[ii][jj] = s;
            }
        }
    }

    // ---- epilogue: logit = b2 + 0.5*(pa+pb+S); sigmoid; zero diag ----
    const float b2v = b2[0];
    float par[8], pbr[8];
    #pragma unroll
    for (int ii = 0; ii < 8; ++ii) par[ii] = pa[i0 + ty + 16 * ii];
    #pragma unroll
    for (int jj = 0; jj < 8; ++jj) pbr[jj] = pb[j0 + tx + 8 * jj];

    #pragma unroll
    for (int ii = 0; ii < 8; ++ii) {
        const int i = i0 + ty + 16 * ii;
        #pragma unroll
        for (int jj = 0; jj < 8; ++jj) {
            const int j = j0 + tx + 8 * jj;
            const float lg = fmaf(0.5f, par[ii] + pbr[jj] + acc[ii][jj], b2v);
            const float sg = 1.0f / (1.0f + __expf(-lg));
            out[(size_t)i * NN + j] = (i == j) ? 0.0f : sg;
        }
    }
}

extern "C" void kernel_launch(void* const* d_in, const int* in_sizes, int n_in,
                              void* d_out, int out_size, void* d_ws, size_t ws_size,
                              hipStream_t stream) {
    const float* nf    = (const float*)d_in[0];
    const float* W_enc = (const float*)d_in[1];
    const float* b_enc = (const float*)d_in[2];
    const float* W1    = (const float*)d_in[3];
    const float* b1    = (const float*)d_in[4];
    const float* W2    = (const float*)d_in[5];
    const float* b2    = (const float*)d_in[6];
    float* out = (float*)d_out;

    float* A  = (float*)d_ws;                 // 2048*64 fp32 (512 KB)
    float* BB = A + (size_t)NN * HIDDEN;      // 512 KB
    float* pa = BB + (size_t)NN * HIDDEN;     // 8 KB
    float* pb = pa + NN;                      // 8 KB

    // Block sizes match __launch_bounds__ exactly (R4 failure mode guard):
    // prep: 256 == 256; pair: 128 == 128.
    prep_kernel<<<NN / 4, 256, 0, stream>>>(nf, W_enc, b_enc, W1, b1, W2,
                                            A, BB, pa, pb);
    pair_kernel<<<dim3(NN / 64, NN / 128), 128, 0, stream>>>(
        A, BB, pa, pb, W2, b2, out);
}

// Round 7
// 99.142 us; speedup vs baseline: 1.1053x; 1.1053x over previous
//
#include <hip/hip_runtime.h>
#include <math.h>

#define NODE_DIM 128
#define HIDDEN   64
#define NN       2048
#define LSTR     68   // floats per LDS row: 64 data + 4 pad (272 B, 16B-aligned)

typedef float v4f __attribute__((ext_vector_type(4)));

// ---------------------------------------------------------------------------
// Prep (R6-verbatim math — PASSED) + tree reduction for the rank-1 sums:
//   h = nf[r] @ W_enc + b_enc
//   A[r]  = h @ W1[:64]          (fp32)
//   BB[r] = h @ W1[64:] + b1     (b1 folded)
//   pa[r] = sum_h W2[h]*A[r,h]   pb[r] = sum_h W2[h]*BB[r,h]
// ---------------------------------------------------------------------------
__global__ __launch_bounds__(256) void prep_kernel(
    const float* __restrict__ nf, const float* __restrict__ W_enc,
    const float* __restrict__ b_enc, const float* __restrict__ W1,
    const float* __restrict__ b1, const float* __restrict__ W2,
    float* __restrict__ A, float* __restrict__ BB,
    float* __restrict__ pa, float* __restrict__ pb)
{
    __shared__ float nf_s[4][NODE_DIM];
    __shared__ float h_s[4][HIDDEN];
    __shared__ float ra_s[4][HIDDEN];
    __shared__ float rb_s[4][HIDDEN];
    const int tid = threadIdx.x;
    const int rg  = tid >> 6;
    const int t   = tid & 63;
    const int r   = blockIdx.x * 4 + rg;

    ((float2*)nf_s[rg])[t] = ((const float2*)(nf + (size_t)r * NODE_DIM))[t];
    __syncthreads();

    float acc = b_enc[t];
    #pragma unroll 8
    for (int k = 0; k < NODE_DIM; ++k)
        acc = fmaf(nf_s[rg][k], W_enc[k * HIDDEN + t], acc);
    h_s[rg][t] = acc;
    __syncthreads();

    float aacc = 0.0f;
    float bacc = b1[t];
    #pragma unroll 8
    for (int k = 0; k < HIDDEN; ++k) {
        const float hv = h_s[rg][k];
        aacc = fmaf(hv, W1[k * HIDDEN + t], aacc);
        bacc = fmaf(hv, W1[(HIDDEN + k) * HIDDEN + t], bacc);
    }
    A[(size_t)r * HIDDEN + t]  = aacc;
    BB[(size_t)r * HIDDEN + t] = bacc;

    const float wv = W2[t];
    ra_s[rg][t] = wv * aacc;
    rb_s[rg][t] = wv * bacc;
    __syncthreads();

    // 6-step LDS tree reduction (uniform barrier count across all 4 groups)
    #pragma unroll
    for (int s = 32; s > 0; s >>= 1) {
        if (t < s) {
            ra_s[rg][t] += ra_s[rg][t + s];
            rb_s[rg][t] += rb_s[rg][t + s];
        }
        __syncthreads();
    }
    if (t == 0) { pa[r] = ra_s[rg][0]; pb[r] = rb_s[rg][0]; }
}

// ---------------------------------------------------------------------------
// Pairwise (R6-verbatim math — PASSED):
//   S[i][j] = sum_h W2[h] * |A[i,h] + BB[j,h]|
//   logit   = b2 + 0.5*(pa[i] + pb[j] + S[i][j])      (relu = (x+|x|)/2)
//   T[i][j] = sigmoid(logit), diagonal zeroed.
// Config fixes vs R6 (the regression): 256 threads (4 waves/block) with
// __launch_bounds__(256,2) -> VGPR cap 256, no spills; #pragma unroll 4 on
// the chunk loop (R6's full unroll blew the allocator); tile 128i x 64j,
// grid 512 = 2 blocks/CU co-resident (LDS 2x52.2 KB < 160) -> 2 waves/SIMD.
// Micro-tile 4i x 8j: i = i0+ty+32*ii (ty 0..31), j = j0+tx+8*jj (tx 0..7).
// Inner loop per 4h: 2x v_pk_add_f32 + 4x v_fma_f32 with abs() src modifier
// (w uniform -> SGPR) = 1.5 instr/h. LDS reads: 8 distinct rows per instr,
// stride 68 -> bank starts {0,4,...,28}, 8-lane broadcast -> conflict-free.
// ---------------------------------------------------------------------------
__global__ __launch_bounds__(256, 2) void pair_kernel(
    const float* __restrict__ A, const float* __restrict__ BB,
    const float* __restrict__ pa, const float* __restrict__ pb,
    const float* __restrict__ W2, const float* __restrict__ b2,
    float* __restrict__ out)
{
    __shared__ __align__(16) float aL[128 * LSTR];   // 34.8 KB
    __shared__ __align__(16) float bL[64 * LSTR];    // 17.4 KB

    const int tid = threadIdx.x;
    const int i0  = blockIdx.y * 128;
    const int j0  = blockIdx.x * 64;

    // ---- stage: A tile 128x64 fp32 (2048 float4), B tile 64x64 (1024) ----
    const v4f* gA = (const v4f*)(A  + (size_t)i0 * HIDDEN);
    const v4f* gB = (const v4f*)(BB + (size_t)j0 * HIDDEN);
    #pragma unroll
    for (int k = 0; k < 8; ++k) {
        const int idx = tid + k * 256;   // 0..2047
        const int row = idx >> 4;        // 16 float4 per row
        const int c   = idx & 15;
        *(v4f*)&aL[row * LSTR + c * 4] = gA[idx];
    }
    #pragma unroll
    for (int k = 0; k < 4; ++k) {
        const int idx = tid + k * 256;   // 0..1023
        const int row = idx >> 4;
        const int c   = idx & 15;
        *(v4f*)&bL[row * LSTR + c * 4] = gB[idx];
    }
    __syncthreads();

    const int ty = tid >> 3;   // 0..31 : i = i0 + ty + 32*ii
    const int tx = tid & 7;    // 0..7  : j = j0 + tx + 8*jj

    float acc[4][8] = {{0.0f}};

    #pragma unroll 4
    for (int c = 0; c < 16; ++c) {       // 4 h per chunk
        const float w0 = W2[c * 4 + 0];  // uniform -> s_load, SGPR operand
        const float w1 = W2[c * 4 + 1];
        const float w2 = W2[c * 4 + 2];
        const float w3 = W2[c * 4 + 3];
        v4f av[4], bv[8];
        #pragma unroll
        for (int ii = 0; ii < 4; ++ii)
            av[ii] = *(const v4f*)&aL[(ty + 32 * ii) * LSTR + c * 4];
        #pragma unroll
        for (int jj = 0; jj < 8; ++jj)
            bv[jj] = *(const v4f*)&bL[(tx + 8 * jj) * LSTR + c * 4];
        #pragma unroll
        for (int ii = 0; ii < 4; ++ii) {
            #pragma unroll
            for (int jj = 0; jj < 8; ++jj) {
                const v4f t = av[ii] + bv[jj];   // 2x v_pk_add_f32
                float s = acc[ii][jj];
                s = fmaf(__builtin_fabsf(t[0]), w0, s);  // v_fma_f32 abs(src0)
                s = fmaf(__builtin_fabsf(t[1]), w1, s);
                s = fmaf(__builtin_fabsf(t[2]), w2, s);
                s = fmaf(__builtin_fabsf(t[3]), w3, s);
                acc[ii][jj] = s;
            }
        }
    }

    // ---- epilogue: logit = b2 + 0.5*(pa+pb+S); sigmoid; zero diag ----
    const float b2v = b2[0];
    float par[4], pbr[8];
    #pragma unroll
    for (int ii = 0; ii < 4; ++ii) par[ii] = pa[i0 + ty + 32 * ii];
    #pragma unroll
    for (int jj = 0; jj < 8; ++jj) pbr[jj] = pb[j0 + tx + 8 * jj];

    #pragma unroll
    for (int ii = 0; ii < 4; ++ii) {
        const int i = i0 + ty + 32 * ii;
        #pragma unroll
        for (int jj = 0; jj < 8; ++jj) {
            const int j = j0 + tx + 8 * jj;
            const float lg = fmaf(0.5f, par[ii] + pbr[jj] + acc[ii][jj], b2v);
            const float sg = 1.0f / (1.0f + __expf(-lg));
            out[(size_t)i * NN + j] = (i == j) ? 0.0f : sg;
        }
    }
}

extern "C" void kernel_launch(void* const* d_in, const int* in_sizes, int n_in,
                              void* d_out, int out_size, void* d_ws, size_t ws_size,
                              hipStream_t stream) {
    const float* nf    = (const float*)d_in[0];
    const float* W_enc = (const float*)d_in[1];
    const float* b_enc = (const float*)d_in[2];
    const float* W1    = (const float*)d_in[3];
    const float* b1    = (const float*)d_in[4];
    const float* W2    = (const float*)d_in[5];
    const float* b2    = (const float*)d_in[6];
    float* out = (float*)d_out;

    float* A  = (float*)d_ws;                 // 2048*64 fp32 (512 KB)
    float* BB = A + (size_t)NN * HIDDEN;      // 512 KB
    float* pa = BB + (size_t)NN * HIDDEN;     // 8 KB
    float* pb = pa + NN;                      // 8 KB

    // Block sizes match __launch_bounds__ exactly (R4 failure-mode guard):
    // prep: 256 == 256; pair: 256 == 256.
    prep_kernel<<<NN / 4, 256, 0, stream>>>(nf, W_enc, b_enc, W1, b1, W2,
                                            A, BB, pa, pb);
    pair_kernel<<<dim3(NN / 64, NN / 128), 256, 0, stream>>>(
        A, BB, pa, pb, W2, b2, out);
}